// Round 2
// baseline (618.039 us; speedup 1.0000x reference)
//
#include <hip/hip_runtime.h>

#define Bn 512
#define Ln 2048
#define Kn 19
#define NEGV (-1000.0f)
#define START_IDn 17
#define PAD_IDn 18
#define CHUNK 256   // backpointer LDS staging chunk (steps)

// ---------------------------------------------------------------------------
// Forward Viterbi: one wave (64 threads) per 2 batches. lane = (half, c) with
// c in [0,32); c<19 are real tags. DP vector lives in LDS (dp[half][0..18]),
// broadcast-read by all lanes each step, updated wave-synchronously (no
// barriers: same-wave DS ops are in-order). Exact op order matches reference:
// cand = DP[p] + T[c][p]  (single f32 add), best = max, new = best + emit,
// argmax = first index attaining best (jnp.argmax tie-break).
//
// R2 change: backpointers staged in LDS (cbuf) and flushed to global every
// CHUNK steps with dwordx4 stores — removes per-step scattered global byte
// stores whose slow completion backed up vmcnt waits on the emission
// prefetch loads (R1: ~410 stall cy/step).
// ---------------------------------------------------------------------------
__global__ __launch_bounds__(64, 1) void crf_fwd(
    const float* __restrict__ P, const float* __restrict__ T,
    const int* __restrict__ mask, unsigned char* __restrict__ choice,
    float* __restrict__ dpfin, int* __restrict__ lens)
{
    const int lane = threadIdx.x;
    const int half = lane >> 5;
    const int c = lane & 31;
    const int b = blockIdx.x * 2 + half;
    const int cc = (c < Kn) ? c : (Kn - 1);

    // Per-lane T row (19 VGPRs)
    float Trow[Kn];
#pragma unroll
    for (int p = 0; p < Kn; ++p) Trow[p] = T[cc * Kn + p];

    // length = sum of mask row (contiguous-prefix mask). 32 lanes per half
    // cooperatively sum 2048 ints with int4 loads, butterfly all-reduce.
    const int* mrow = mask + (size_t)b * Ln;
    int sum = 0;
#pragma unroll
    for (int j = 0; j < Ln / 128; ++j) {
        int4 v = *(const int4*)(mrow + j * 128 + c * 4);
        sum += v.x + v.y + v.z + v.w;
    }
#pragma unroll
    for (int k = 1; k < 32; k <<= 1) sum += __shfl_xor(sum, k, 64);
    const int len = sum;                 // per-half value (all 32 lanes have it)
    if (c == 0) lens[b] = len;
    const int lenO = __shfl_xor(len, 32, 64);
    int maxlen = len > lenO ? len : lenO;
    int mlen = (maxlen + 7) & ~7;        // unroll-8 padded; <= 2048 always
    mlen = __builtin_amdgcn_readfirstlane(mlen);

    __shared__ float dp[2][32];                       // 128B rows, 16B aligned
    __shared__ unsigned char cbuf[2][CHUNK * Kn];     // 2 x 4864 B staging
    float mydp = (c == START_IDn) ? 0.0f : NEGV;
    dp[half][c] = mydp;

    const float* prow = P + (size_t)b * Ln * Kn;
    unsigned char* crow = choice + (size_t)b * Ln * Kn;

    // rolling emission prefetch (depth 8, static register indices via unroll)
    float eb[8];
#pragma unroll
    for (int u = 0; u < 8; ++u) eb[u] = prow[u * Kn + cc];

    for (int t0 = 0; t0 < mlen; t0 += CHUNK) {
        int tend = mlen - t0;
        if (tend > CHUNK) tend = CHUNK;              // multiple of 8
        for (int tt = 0; tt < tend; tt += 8) {
#pragma unroll
            for (int u = 0; u < 8; ++u) {
                const int t = t0 + tt + u;
                const float e = eb[u];

                const float* base = &dp[half][0];
                float4 q0 = *(const float4*)(base + 0);
                float4 q1 = *(const float4*)(base + 4);
                float4 q2 = *(const float4*)(base + 8);
                float4 q3 = *(const float4*)(base + 12);
                float4 q4 = *(const float4*)(base + 16);  // .w = lane19 junk, unused

                float cand[Kn];
                cand[0]  = q0.x + Trow[0];  cand[1]  = q0.y + Trow[1];
                cand[2]  = q0.z + Trow[2];  cand[3]  = q0.w + Trow[3];
                cand[4]  = q1.x + Trow[4];  cand[5]  = q1.y + Trow[5];
                cand[6]  = q1.z + Trow[6];  cand[7]  = q1.w + Trow[7];
                cand[8]  = q2.x + Trow[8];  cand[9]  = q2.y + Trow[9];
                cand[10] = q2.z + Trow[10]; cand[11] = q2.w + Trow[11];
                cand[12] = q3.x + Trow[12]; cand[13] = q3.y + Trow[13];
                cand[14] = q3.z + Trow[14]; cand[15] = q3.w + Trow[15];
                cand[16] = q4.x + Trow[16]; cand[17] = q4.y + Trow[17];
                cand[18] = q4.z + Trow[18];

                // max tree, depth 3 (compiler fuses pairs into v_max3_f32)
                float m0 = fmaxf(fmaxf(cand[0],  cand[1]),  cand[2]);
                float m1 = fmaxf(fmaxf(cand[3],  cand[4]),  cand[5]);
                float m2 = fmaxf(fmaxf(cand[6],  cand[7]),  cand[8]);
                float m3 = fmaxf(fmaxf(cand[9],  cand[10]), cand[11]);
                float m4 = fmaxf(fmaxf(cand[12], cand[13]), cand[14]);
                float m5 = fmaxf(fmaxf(cand[15], cand[16]), cand[17]);
                float n0 = fmaxf(fmaxf(m0, m1), m2);
                float n1 = fmaxf(fmaxf(m3, m4), cand[18]);
                float best = fmaxf(fmaxf(n0, n1), m5);

                // first-index argmax (exact equality vs best) — off critical path
                int arg = Kn - 1;
#pragma unroll
                for (int p = Kn - 2; p >= 0; --p)
                    arg = (cand[p] == best) ? p : arg;

                // masked update; mask is contiguous prefix -> t<len compare
                float nd = best + e;
                mydp = (t < len) ? nd : mydp;
                dp[half][c] = mydp;               // wave-synchronous LDS update

                if (c < Kn) cbuf[half][(tt + u) * Kn + c] = (unsigned char)arg;

                // prefetch emission for t+8 (clamped address; value unused past end)
                int tn = t + 8;
                int tcl = tn < Ln ? tn : Ln - 1;
                eb[u] = prow[tcl * Kn + cc];
            }
        }
        // bulk flush of this chunk's backpointers (full 4864B even when
        // tend<CHUNK: trailing garbage lands in rows >= len, never read)
        {
            const int4* s = (const int4*)&cbuf[half][0];
            int4* d = (int4*)(crow + (size_t)t0 * Kn);
            for (int i = c; i < (CHUNK * Kn) / 16; i += 32) d[i] = s[i];
        }
    }
    if (c < Kn) dpfin[b * Kn + c] = mydp;   // DP frozen beyond len == final DP
}

// ---------------------------------------------------------------------------
// Backtrace: one block per batch. Exact integer function-composition scan:
//   g_t(x) = choice[t][x];  S_t = g_t o S_{t+1} (identity for t >= len)
//   path[t] = S_{t+1}(last) for t < len, else -1.
// Phase 1: 16 chunks x 128 steps composed in-place in LDS; each chunk's 19
// tag-lanes live inside one wave (3 chunks/wave) -> no per-step barriers.
// Phase 2: 16-step sequential chunk-boundary chain (thread 0).
// Phase 3: fully parallel emission out[t] = comp[t+1][ vchain[(t+1)/128 + 1] ].
// ---------------------------------------------------------------------------
__global__ __launch_bounds__(384, 1) void crf_bwd(
    const float* __restrict__ T, const unsigned char* __restrict__ choice,
    const float* __restrict__ dpfin, const int* __restrict__ lens,
    int* __restrict__ out)
{
    __shared__ unsigned char comp[Ln * Kn];   // 38912 B
    __shared__ int vchain[17];
    __shared__ int s_last, s_len;

    const int b = blockIdx.x;
    const int tid = threadIdx.x;

    // load this batch's backpointers into LDS (rows >= len hold garbage,
    // discarded by the t<len guard below)
    {
        const int4* src = (const int4*)(choice + (size_t)b * Ln * Kn);
        int4* dst = (int4*)comp;
        for (int i = tid; i < (Ln * Kn) / 16; i += 384) dst[i] = src[i];
    }
    if (tid == 0) {
        s_len = lens[b];
        // last = argmax_c( DPfinal[c] + T[PAD][c] ), first-index tie-break
        float bestv = dpfin[b * Kn + 0] + T[PAD_IDn * Kn + 0];
        int bl = 0;
        for (int ci = 1; ci < Kn; ++ci) {
            float v = dpfin[b * Kn + ci] + T[PAD_IDn * Kn + ci];
            if (v > bestv) { bestv = v; bl = ci; }
        }
        s_last = bl;
    }
    __syncthreads();
    const int len = s_len;

    // Phase 1: suffix-compose within each chunk, in place.
    {
        const int wv = tid >> 6;
        const int lane = tid & 63;
        const int ch = wv * 3 + lane / Kn;
        const int c = lane % Kn;
        if (lane < 3 * Kn && ch < 16) {
            int cur = c;                       // identity
            const int tb = ch * 128 + 127;
            for (int i = 0; i < 128; ++i) {
                const int t = tb - i;
                int nv = comp[t * Kn + cur];   // read g_t (in-bounds always)
                cur = (t < len) ? nv : cur;    // g_t = id for t >= len
                comp[t * Kn + c] = cur;        // overwrite row t with C_[t,b)
            }
        }
    }
    __syncthreads();

    // Phase 2: chunk-boundary values v[ch] = S_{ch*128}(last)
    if (tid == 0) {
        int v = s_last;
        vchain[16] = v;
        for (int ch = 15; ch >= 0; --ch) {
            v = comp[ch * 128 * Kn + v];
            vchain[ch] = v;
        }
    }
    __syncthreads();

    // Phase 3: emit path
    const int last = s_last;
    int* orow = out + (size_t)b * Ln;
    for (int t = tid; t < Ln; t += 384) {
        int val;
        if (t >= len) {
            val = -1;
        } else if (t == Ln - 1) {
            val = last;                        // only reachable when len == L
        } else {
            const int tp = t + 1;
            const int vc = vchain[(tp >> 7) + 1];
            val = comp[tp * Kn + vc];
        }
        orow[t] = val;
    }
}

// ---------------------------------------------------------------------------
extern "C" void kernel_launch(void* const* d_in, const int* in_sizes, int n_in,
                              void* d_out, int out_size, void* d_ws, size_t ws_size,
                              hipStream_t stream)
{
    const float* P    = (const float*)d_in[0];
    const float* T    = (const float*)d_in[1];
    const int*   mask = (const int*)d_in[2];
    int* out = (int*)d_out;

    // workspace layout
    const size_t choice_bytes = (size_t)Bn * Ln * Kn;          // 19,922,944
    unsigned char* choice = (unsigned char*)d_ws;
    float* dpfin = (float*)((char*)d_ws + choice_bytes);       // 512*19*4
    int* lens = (int*)((char*)d_ws + choice_bytes + (size_t)Bn * Kn * 4);

    crf_fwd<<<Bn / 2, 64, 0, stream>>>(P, T, mask, choice, dpfin, lens);
    crf_bwd<<<Bn, 384, 0, stream>>>(T, choice, dpfin, lens, out);
}

// Round 3
// 606.133 us; speedup vs baseline: 1.0196x; 1.0196x over previous
//
#include <hip/hip_runtime.h>

#define Bn 512
#define Ln 2048
#define Kn 19
#define NEGV (-1000.0f)
#define START_IDn 17
#define PAD_IDn 18
#define CHUNK 256            // backpointer flush granularity (steps)
#define ECH 32               // emission LDS staging chunk (steps)
#define PBYTES 79691776u     // 512*2048*19*4

// ---------------------------------------------------------------------------
// Forward Viterbi: one wave per 2 batches. lane = (half, c), c in [0,32);
// c<19 real tags. DP vector in LDS, broadcast-read each step (wave-synchronous,
// no barriers). Exact reference op order: cand = DP[p]+T[c][p], best = max,
// new = best+emit, first-index argmax tie-break.
//
// R3: zero per-step VMEM. Emissions staged through LDS in double-buffered
// 32-step chunks (5 dwordx4 loads/lane issued a full chunk ahead, LDS write at
// chunk end); per-step emission is one ds_read_b32 that shares the dp lgkm
// wait. R1/R2 showed ~420 stall cy/step with a per-step rolling global load —
// vmcnt exposure suspected (87 GB/s == microscopic effective load depth).
// ---------------------------------------------------------------------------
__global__ __launch_bounds__(64, 1) void crf_fwd(
    const float* __restrict__ P, const float* __restrict__ T,
    const int* __restrict__ mask, unsigned char* __restrict__ choice,
    float* __restrict__ dpfin, int* __restrict__ lens)
{
    const int lane = threadIdx.x;
    const int half = lane >> 5;
    const int c = lane & 31;
    const int b = blockIdx.x * 2 + half;
    const int cc = (c < Kn) ? c : (Kn - 1);

    // Per-lane T row
    float Trow[Kn];
#pragma unroll
    for (int p = 0; p < Kn; ++p) Trow[p] = T[cc * Kn + p];

    // length = popcount of contiguous-prefix mask row
    const int* mrow = mask + (size_t)b * Ln;
    int sum = 0;
#pragma unroll
    for (int j = 0; j < Ln / 128; ++j) {
        int4 v = *(const int4*)(mrow + j * 128 + c * 4);
        sum += v.x + v.y + v.z + v.w;
    }
#pragma unroll
    for (int k = 1; k < 32; k <<= 1) sum += __shfl_xor(sum, k, 64);
    const int len = sum;
    if (c == 0) lens[b] = len;
    const int lenO = __shfl_xor(len, 32, 64);
    int maxlen = len > lenO ? len : lenO;
    int mlen = (maxlen + (ECH - 1)) & ~(ECH - 1);   // multiple of 32, <= 2048
    mlen = __builtin_amdgcn_readfirstlane(mlen);

    __shared__ float dp[2][32];                     // 16B-aligned rows
    __shared__ unsigned char cbuf[2][CHUNK * Kn];   // backpointer staging
    __shared__ float ebuf[2][2][ECH * Kn + 32];     // [buf][half][608 + pad]

    float mydp = (c == START_IDn) ? 0.0f : NEGV;
    dp[half][c] = mydp;

    unsigned char* crow = choice + (size_t)b * Ln * Kn;
    const unsigned rowbytes = Ln * Kn * 4;          // 155648
    const unsigned bbyte = (unsigned)b * rowbytes;

    // --- emission staging: 5 x dwordx4 per lane per 32-step chunk ---------
    float4 r0, r1, r2, r3, r4;
    const unsigned limit = PBYTES - 16;
    const char* Pc = (const char*)P;

#define STAGE_LOAD(chunkIdx)                                                   \
    {                                                                          \
        unsigned base_ = bbyte + (unsigned)(chunkIdx) * (ECH * Kn * 4)         \
                       + ((unsigned)c << 4);                                   \
        unsigned o0 = base_ + 0 * 512; if (o0 > limit) o0 = limit;             \
        unsigned o1 = base_ + 1 * 512; if (o1 > limit) o1 = limit;             \
        unsigned o2 = base_ + 2 * 512; if (o2 > limit) o2 = limit;             \
        unsigned o3 = base_ + 3 * 512; if (o3 > limit) o3 = limit;             \
        unsigned o4 = base_ + 4 * 512; if (o4 > limit) o4 = limit;             \
        r0 = *(const float4*)(Pc + o0);                                        \
        r1 = *(const float4*)(Pc + o1);                                        \
        r2 = *(const float4*)(Pc + o2);                                        \
        r3 = *(const float4*)(Pc + o3);                                        \
        r4 = *(const float4*)(Pc + o4);                                        \
    }

#define STAGE_WRITE(nb)                                                        \
    {                                                                          \
        float* d_ = &ebuf[nb][half][(unsigned)c << 2];                         \
        *(float4*)(d_ + 0 * 128) = r0;                                         \
        *(float4*)(d_ + 1 * 128) = r1;                                         \
        *(float4*)(d_ + 2 * 128) = r2;                                         \
        *(float4*)(d_ + 3 * 128) = r3;                                         \
        *(float4*)(d_ + 4 * 128) = r4;                                         \
    }

    int buf = 0;
    STAGE_LOAD(0);
    STAGE_WRITE(0);

    for (int t0 = 0; t0 < mlen; t0 += CHUNK) {
        int tend = mlen - t0;
        if (tend > CHUNK) tend = CHUNK;             // multiple of ECH
        for (int ck = 0; ck < tend; ck += ECH) {
            const int tb = t0 + ck;
            STAGE_LOAD(tb / ECH + 1);               // prefetch next chunk
            for (int tt = 0; tt < ECH; tt += 8) {
#pragma unroll
                for (int u = 0; u < 8; ++u) {
                    const int t = tb + tt + u;
                    const float e = ebuf[buf][half][(tt + u) * Kn + cc];

                    const float* base = &dp[half][0];
                    float4 q0 = *(const float4*)(base + 0);
                    float4 q1 = *(const float4*)(base + 4);
                    float4 q2 = *(const float4*)(base + 8);
                    float4 q3 = *(const float4*)(base + 12);
                    float4 q4 = *(const float4*)(base + 16); // .w junk, unused

                    float cand[Kn];
                    cand[0]  = q0.x + Trow[0];  cand[1]  = q0.y + Trow[1];
                    cand[2]  = q0.z + Trow[2];  cand[3]  = q0.w + Trow[3];
                    cand[4]  = q1.x + Trow[4];  cand[5]  = q1.y + Trow[5];
                    cand[6]  = q1.z + Trow[6];  cand[7]  = q1.w + Trow[7];
                    cand[8]  = q2.x + Trow[8];  cand[9]  = q2.y + Trow[9];
                    cand[10] = q2.z + Trow[10]; cand[11] = q2.w + Trow[11];
                    cand[12] = q3.x + Trow[12]; cand[13] = q3.y + Trow[13];
                    cand[14] = q3.z + Trow[14]; cand[15] = q3.w + Trow[15];
                    cand[16] = q4.x + Trow[16]; cand[17] = q4.y + Trow[17];
                    cand[18] = q4.z + Trow[18];

                    float m0 = fmaxf(fmaxf(cand[0],  cand[1]),  cand[2]);
                    float m1 = fmaxf(fmaxf(cand[3],  cand[4]),  cand[5]);
                    float m2 = fmaxf(fmaxf(cand[6],  cand[7]),  cand[8]);
                    float m3 = fmaxf(fmaxf(cand[9],  cand[10]), cand[11]);
                    float m4 = fmaxf(fmaxf(cand[12], cand[13]), cand[14]);
                    float m5 = fmaxf(fmaxf(cand[15], cand[16]), cand[17]);
                    float n0 = fmaxf(fmaxf(m0, m1), m2);
                    float n1 = fmaxf(fmaxf(m3, m4), cand[18]);
                    float best = fmaxf(fmaxf(n0, n1), m5);

                    // dp update first: shortens write->read turnaround
                    float nd = best + e;
                    mydp = (t < len) ? nd : mydp;
                    dp[half][c] = mydp;

                    // first-index argmax — off the serial chain; scheduler can
                    // overlap it with next step's LDS latency
                    int arg = Kn - 1;
#pragma unroll
                    for (int p = Kn - 2; p >= 0; --p)
                        arg = (cand[p] == best) ? p : arg;
                    if (c < Kn) cbuf[half][(ck + tt + u) * Kn + c] = (unsigned char)arg;
                }
            }
            STAGE_WRITE(buf ^ 1);                   // vmcnt wait lands here
            buf ^= 1;
        }
        // bulk flush of this 256-step block's backpointers (rows >= len hold
        // garbage, never read by backtrace)
        {
            const int4* s = (const int4*)&cbuf[half][0];
            int4* d = (int4*)(crow + (size_t)t0 * Kn);
            for (int i = c; i < (CHUNK * Kn) / 16; i += 32) d[i] = s[i];
        }
    }
    if (c < Kn) dpfin[b * Kn + c] = mydp;
#undef STAGE_LOAD
#undef STAGE_WRITE
}

// ---------------------------------------------------------------------------
// Backtrace: unchanged from R2 (exact integer function-composition scan).
// ---------------------------------------------------------------------------
__global__ __launch_bounds__(384, 1) void crf_bwd(
    const float* __restrict__ T, const unsigned char* __restrict__ choice,
    const float* __restrict__ dpfin, const int* __restrict__ lens,
    int* __restrict__ out)
{
    __shared__ unsigned char comp[Ln * Kn];   // 38912 B
    __shared__ int vchain[17];
    __shared__ int s_last, s_len;

    const int b = blockIdx.x;
    const int tid = threadIdx.x;

    {
        const int4* src = (const int4*)(choice + (size_t)b * Ln * Kn);
        int4* dst = (int4*)comp;
        for (int i = tid; i < (Ln * Kn) / 16; i += 384) dst[i] = src[i];
    }
    if (tid == 0) {
        s_len = lens[b];
        float bestv = dpfin[b * Kn + 0] + T[PAD_IDn * Kn + 0];
        int bl = 0;
        for (int ci = 1; ci < Kn; ++ci) {
            float v = dpfin[b * Kn + ci] + T[PAD_IDn * Kn + ci];
            if (v > bestv) { bestv = v; bl = ci; }
        }
        s_last = bl;
    }
    __syncthreads();
    const int len = s_len;

    // Phase 1: suffix-compose within each 128-step chunk, in place.
    {
        const int wv = tid >> 6;
        const int lane = tid & 63;
        const int ch = wv * 3 + lane / Kn;
        const int c = lane % Kn;
        if (lane < 3 * Kn && ch < 16) {
            int cur = c;
            const int tb = ch * 128 + 127;
            for (int i = 0; i < 128; ++i) {
                const int t = tb - i;
                int nv = comp[t * Kn + cur];
                cur = (t < len) ? nv : cur;
                comp[t * Kn + c] = cur;
            }
        }
    }
    __syncthreads();

    // Phase 2: chunk-boundary chain
    if (tid == 0) {
        int v = s_last;
        vchain[16] = v;
        for (int ch = 15; ch >= 0; --ch) {
            v = comp[ch * 128 * Kn + v];
            vchain[ch] = v;
        }
    }
    __syncthreads();

    // Phase 3: emit path
    const int last = s_last;
    int* orow = out + (size_t)b * Ln;
    for (int t = tid; t < Ln; t += 384) {
        int val;
        if (t >= len) {
            val = -1;
        } else if (t == Ln - 1) {
            val = last;
        } else {
            const int tp = t + 1;
            const int vc = vchain[(tp >> 7) + 1];
            val = comp[tp * Kn + vc];
        }
        orow[t] = val;
    }
}

// ---------------------------------------------------------------------------
extern "C" void kernel_launch(void* const* d_in, const int* in_sizes, int n_in,
                              void* d_out, int out_size, void* d_ws, size_t ws_size,
                              hipStream_t stream)
{
    const float* P    = (const float*)d_in[0];
    const float* T    = (const float*)d_in[1];
    const int*   mask = (const int*)d_in[2];
    int* out = (int*)d_out;

    const size_t choice_bytes = (size_t)Bn * Ln * Kn;          // 19,922,944
    unsigned char* choice = (unsigned char*)d_ws;
    float* dpfin = (float*)((char*)d_ws + choice_bytes);
    int* lens = (int*)((char*)d_ws + choice_bytes + (size_t)Bn * Kn * 4);

    crf_fwd<<<Bn / 2, 64, 0, stream>>>(P, T, mask, choice, dpfin, lens);
    crf_bwd<<<Bn, 384, 0, stream>>>(T, choice, dpfin, lens, out);
}

// Round 5
// 398.192 us; speedup vs baseline: 1.5521x; 1.5222x over previous
//
#include <hip/hip_runtime.h>

#define Bn 512
#define Ln 2048
#define Kn 19
#define NEGV (-1000.0f)
#define START_IDn 17
#define PAD_IDn 18
#define SEG 64               // checkpoint / staging segment (steps)
#define PBYTES 79691776u     // 512*2048*19*4

// ---------------------------------------------------------------------------
// R5 = R4 structure with dpck relocated into d_out (R4's container crash was
// plausibly a d_ws overflow: ws use grew past the R1-R3-proven 19.96 MB).
//   1. crf_fwd — serial Viterbi DP only (no argmax/choice writes); 19-float
//                DP checkpoint every 64 steps. ~37 wave-instrs/step vs 90.
//   2. crf_rec — 512x32 independent 64-step segments re-run from checkpoints
//                at high occupancy; bit-exact recompute; writes backpointers.
//   3. crf_bwd — unchanged function-composition backtrace; overwrites d_out.
// Evidence basis: R2/R3 neutral => solo-wave cadence-bound (~6.6 cy/instr),
// per-step time tracks instruction count, not memory source.
// ---------------------------------------------------------------------------

// Shared per-step core: cand[p] = dp[p] + Trow[p] (exact reference op order),
// best = depth-3 max tree (v_max3). Argmax only in crf_rec.
#define DP_CORE(BASE)                                                          \
    float4 q0 = *(const float4*)((BASE) + 0);                                  \
    float4 q1 = *(const float4*)((BASE) + 4);                                  \
    float4 q2 = *(const float4*)((BASE) + 8);                                  \
    float4 q3 = *(const float4*)((BASE) + 12);                                 \
    float4 q4 = *(const float4*)((BASE) + 16); /* .w junk, unused */           \
    float cand[Kn];                                                            \
    cand[0]  = q0.x + Trow[0];  cand[1]  = q0.y + Trow[1];                     \
    cand[2]  = q0.z + Trow[2];  cand[3]  = q0.w + Trow[3];                     \
    cand[4]  = q1.x + Trow[4];  cand[5]  = q1.y + Trow[5];                     \
    cand[6]  = q1.z + Trow[6];  cand[7]  = q1.w + Trow[7];                     \
    cand[8]  = q2.x + Trow[8];  cand[9]  = q2.y + Trow[9];                     \
    cand[10] = q2.z + Trow[10]; cand[11] = q2.w + Trow[11];                    \
    cand[12] = q3.x + Trow[12]; cand[13] = q3.y + Trow[13];                    \
    cand[14] = q3.z + Trow[14]; cand[15] = q3.w + Trow[15];                    \
    cand[16] = q4.x + Trow[16]; cand[17] = q4.y + Trow[17];                    \
    cand[18] = q4.z + Trow[18];                                                \
    float m0 = fmaxf(fmaxf(cand[0],  cand[1]),  cand[2]);                      \
    float m1 = fmaxf(fmaxf(cand[3],  cand[4]),  cand[5]);                      \
    float m2 = fmaxf(fmaxf(cand[6],  cand[7]),  cand[8]);                      \
    float m3 = fmaxf(fmaxf(cand[9],  cand[10]), cand[11]);                     \
    float m4 = fmaxf(fmaxf(cand[12], cand[13]), cand[14]);                     \
    float m5 = fmaxf(fmaxf(cand[15], cand[16]), cand[17]);                     \
    float n0 = fmaxf(fmaxf(m0, m1), m2);                                       \
    float n1 = fmaxf(fmaxf(m3, m4), cand[18]);                                 \
    float best = fmaxf(fmaxf(n0, n1), m5);

// ---------------------------------------------------------------------------
__global__ __launch_bounds__(64, 1) void crf_fwd(
    const float* __restrict__ P, const float* __restrict__ T,
    const int* __restrict__ mask, float* __restrict__ dpck,
    float* __restrict__ dpfin, int* __restrict__ lens)
{
    const int lane = threadIdx.x;
    const int half = lane >> 5;
    const int c = lane & 31;
    const int b = blockIdx.x * 2 + half;
    const int cc = (c < Kn) ? c : (Kn - 1);

    float Trow[Kn];
#pragma unroll
    for (int p = 0; p < Kn; ++p) Trow[p] = T[cc * Kn + p];

    // length = popcount of contiguous-prefix mask row
    const int* mrow = mask + (size_t)b * Ln;
    int sum = 0;
#pragma unroll
    for (int j = 0; j < Ln / 128; ++j) {
        int4 v = *(const int4*)(mrow + j * 128 + c * 4);
        sum += v.x + v.y + v.z + v.w;
    }
#pragma unroll
    for (int k = 1; k < 32; k <<= 1) sum += __shfl_xor(sum, k, 64);
    const int len = sum;
    if (c == 0) lens[b] = len;
    const int lenO = __shfl_xor(len, 32, 64);
    int maxlen = len > lenO ? len : lenO;
    int lmin = len < lenO ? len : lenO;
    lmin = __builtin_amdgcn_readfirstlane(lmin);
    int mlen = (maxlen + (SEG - 1)) & ~(SEG - 1);
    mlen = __builtin_amdgcn_readfirstlane(mlen);

    __shared__ float dp[2][32];
    __shared__ float ebuf[2][2][1280];   // [buf][half]; 64*19=1216 used + pad

    float mydp = (c == START_IDn) ? 0.0f : NEGV;
    dp[half][c] = mydp;

    const unsigned bbyte = (unsigned)b * (Ln * Kn * 4u);
    const unsigned limit = PBYTES - 16;
    const char* Pc = (const char*)P;
    float4 r[10];

#define STAGE_LOAD(ci)                                                         \
    { unsigned base_ = bbyte + (unsigned)(ci) * 4864u + ((unsigned)c << 4);    \
      _Pragma("unroll")                                                        \
      for (int i_ = 0; i_ < 10; ++i_) {                                        \
          unsigned o_ = base_ + (unsigned)i_ * 512u;                           \
          if (o_ > limit) o_ = limit;                                          \
          r[i_] = *(const float4*)(Pc + o_);                                   \
      } }
#define STAGE_WRITE(nb)                                                        \
    { float* d_ = &ebuf[nb][half][(unsigned)c << 2];                           \
      _Pragma("unroll")                                                        \
      for (int i_ = 0; i_ < 10; ++i_) *(float4*)(d_ + i_ * 128) = r[i_]; }

    int buf = 0;
    STAGE_LOAD(0);
    STAGE_WRITE(0);

    for (int t0 = 0; t0 < mlen; t0 += SEG) {
        // checkpoint: DP entering step t0 (includes initial DP at t0=0)
        if (c < Kn)
            dpck[((unsigned)b * 32u + (unsigned)(t0 >> 6)) * (unsigned)Kn + (unsigned)c] = mydp;
        STAGE_LOAD((t0 >> 6) + 1);       // prefetch next segment's emissions
        const float* ebl = &ebuf[buf][half][0];

        if (t0 + SEG <= lmin) {
            // fast path: every step strictly below both lengths — no mask
            for (int tt = 0; tt < SEG; tt += 8) {
#pragma unroll
                for (int u = 0; u < 8; ++u) {
                    const float e = ebl[(tt + u) * Kn + cc];
                    const float* base_ = &dp[half][0];
                    DP_CORE(base_)
                    mydp = best + e;
                    dp[half][c] = mydp;
                }
            }
        } else {
            for (int tt = 0; tt < SEG; tt += 8) {
#pragma unroll
                for (int u = 0; u < 8; ++u) {
                    const int t = t0 + tt + u;
                    const float e = ebl[(tt + u) * Kn + cc];
                    const float* base_ = &dp[half][0];
                    DP_CORE(base_)
                    float nd = best + e;
                    mydp = (t < len) ? nd : mydp;   // frozen past sequence end
                    dp[half][c] = mydp;
                }
            }
        }
        STAGE_WRITE(buf ^ 1);
        buf ^= 1;
    }
    if (c < Kn) dpfin[b * Kn + c] = mydp;
#undef STAGE_LOAD
#undef STAGE_WRITE
}

// ---------------------------------------------------------------------------
// Recompute backpointers: task = (batch, segment); 32-lane half-wave per task,
// 8 tasks per 256-thread block. High occupancy hides all latencies; per-step
// math is bit-identical to crf_fwd (same inputs, same op order), so argmax
// reproduces the exact backpointers the fused kernel would have produced.
// ---------------------------------------------------------------------------
__global__ __launch_bounds__(256) void crf_rec(
    const float* __restrict__ P, const float* __restrict__ T,
    const float* __restrict__ dpck, const int* __restrict__ lens,
    unsigned char* __restrict__ choice)
{
    const int tid = threadIdx.x;
    const int halfid = tid >> 5;
    const int c = tid & 31;
    const int cc = (c < Kn) ? c : (Kn - 1);
    const int task = blockIdx.x * 8 + halfid;   // < 16384
    const int b = task >> 5;
    const int seg = task & 31;
    const int t0 = seg * SEG;
    const int len = lens[b];
    if (t0 >= len) return;                      // rows never read by backtrace

    __shared__ float dp[8][32];
    __shared__ __align__(16) unsigned char cbuf[8][SEG * Kn];  // 8 x 1216

    float Trow[Kn];
#pragma unroll
    for (int p = 0; p < Kn; ++p) Trow[p] = T[cc * Kn + p];

    float mydp = (c < Kn) ? dpck[((unsigned)b * 32u + (unsigned)seg) * (unsigned)Kn + (unsigned)c]
                          : NEGV;
    dp[halfid][c] = mydp;

    const float* prow = P + (size_t)b * Ln * Kn + (size_t)t0 * Kn;

    // rolling emission prefetch (depth 8)
    float eb[8];
#pragma unroll
    for (int u = 0; u < 8; ++u) eb[u] = prow[u * Kn + cc];

    for (int tt = 0; tt < SEG; tt += 8) {
#pragma unroll
        for (int u = 0; u < 8; ++u) {
            const int t = t0 + tt + u;
            const float e = eb[u];
            const float* base_ = &dp[halfid][0];
            DP_CORE(base_)
            float nd = best + e;
            mydp = (t < len) ? nd : mydp;
            dp[halfid][c] = mydp;

            // first-index argmax (jnp.argmax tie-break), exact equality
            int arg = Kn - 1;
#pragma unroll
            for (int p = Kn - 2; p >= 0; --p)
                arg = (cand[p] == best) ? p : arg;
            if (c < Kn) cbuf[halfid][(tt + u) * Kn + c] = (unsigned char)arg;

            // prefetch emission for local step tt+u+8 (clamped in-bounds)
            int tn = tt + u + 8;
            int tloc = (t0 + tn < Ln) ? tn : (Ln - 1 - t0);
            eb[u] = prow[tloc * Kn + cc];
        }
    }
    // bulk flush this segment's backpointers (steps >= len garbage, unread)
    {
        const int4* s = (const int4*)&cbuf[halfid][0];
        int4* d = (int4*)(choice + (size_t)b * Ln * Kn + (size_t)t0 * Kn);
        for (int i = c; i < (SEG * Kn) / 16; i += 32) d[i] = s[i];
    }
}

// ---------------------------------------------------------------------------
// Backtrace: unchanged (exact integer function-composition scan).
// ---------------------------------------------------------------------------
__global__ __launch_bounds__(384, 1) void crf_bwd(
    const float* __restrict__ T, const unsigned char* __restrict__ choice,
    const float* __restrict__ dpfin, const int* __restrict__ lens,
    int* __restrict__ out)
{
    __shared__ unsigned char comp[Ln * Kn];   // 38912 B
    __shared__ int vchain[17];
    __shared__ int s_last, s_len;

    const int b = blockIdx.x;
    const int tid = threadIdx.x;

    {
        const int4* src = (const int4*)(choice + (size_t)b * Ln * Kn);
        int4* dst = (int4*)comp;
        for (int i = tid; i < (Ln * Kn) / 16; i += 384) dst[i] = src[i];
    }
    if (tid == 0) {
        s_len = lens[b];
        float bestv = dpfin[b * Kn + 0] + T[PAD_IDn * Kn + 0];
        int bl = 0;
        for (int ci = 1; ci < Kn; ++ci) {
            float v = dpfin[b * Kn + ci] + T[PAD_IDn * Kn + ci];
            if (v > bestv) { bestv = v; bl = ci; }
        }
        s_last = bl;
    }
    __syncthreads();
    const int len = s_len;

    // Phase 1: suffix-compose within each 128-step chunk, in place.
    // Rows t >= len compose to identity (g_t = id), so garbage in those
    // choice rows is read-then-discarded, never propagated.
    {
        const int wv = tid >> 6;
        const int lane = tid & 63;
        const int ch = wv * 3 + lane / Kn;
        const int c = lane % Kn;
        if (lane < 3 * Kn && ch < 16) {
            int cur = c;
            const int tb = ch * 128 + 127;
            for (int i = 0; i < 128; ++i) {
                const int t = tb - i;
                int nv = comp[t * Kn + cur];   // cur <= 18 always: in-bounds
                cur = (t < len) ? nv : cur;
                comp[t * Kn + c] = cur;
            }
        }
    }
    __syncthreads();

    // Phase 2: chunk-boundary chain
    if (tid == 0) {
        int v = s_last;
        vchain[16] = v;
        for (int ch = 15; ch >= 0; --ch) {
            v = comp[ch * 128 * Kn + v];
            vchain[ch] = v;
        }
    }
    __syncthreads();

    // Phase 3: emit path
    const int last = s_last;
    int* orow = out + (size_t)b * Ln;
    for (int t = tid; t < Ln; t += 384) {
        int val;
        if (t >= len) {
            val = -1;
        } else if (t == Ln - 1) {
            val = last;
        } else {
            const int tp = t + 1;
            const int vc = vchain[(tp >> 7) + 1];
            val = comp[tp * Kn + vc];
        }
        orow[t] = val;
    }
}

// ---------------------------------------------------------------------------
extern "C" void kernel_launch(void* const* d_in, const int* in_sizes, int n_in,
                              void* d_out, int out_size, void* d_ws, size_t ws_size,
                              hipStream_t stream)
{
    const float* P    = (const float*)d_in[0];
    const float* T    = (const float*)d_in[1];
    const int*   mask = (const int*)d_in[2];
    int* out = (int*)d_out;

    // workspace layout — identical footprint to R1-R3 (19,963,904 B proven ok)
    const size_t choice_bytes = (size_t)Bn * Ln * Kn;            // 19,922,944
    unsigned char* choice = (unsigned char*)d_ws;
    float* dpfin = (float*)((char*)d_ws + choice_bytes);         // 38,912 B
    int* lens = (int*)((char*)d_ws + choice_bytes + (size_t)Bn * Kn * 4);

    // dpck (1,245,184 B) lives in d_out (4 MB): written by crf_fwd, read by
    // crf_rec, then d_out is fully overwritten by crf_bwd. Stream-ordered.
    float* dpck = (float*)((char*)d_out + 2 * 1024 * 1024);

    crf_fwd<<<Bn / 2, 64, 0, stream>>>(P, T, mask, dpck, dpfin, lens);
    crf_rec<<<(Bn * 32) / 8, 256, 0, stream>>>(P, T, dpck, lens, choice);
    crf_bwd<<<Bn, 384, 0, stream>>>(T, choice, dpfin, lens, out);
}